// Round 6
// baseline (259.638 us; speedup 1.0000x reference)
//
#include <hip/hip_runtime.h>
#include <math.h>

#define NL  1024     // N_LEVELS
#define KP1 9        // K+1
#define NB  4096     // direct-mapped buckets (8 KB u16 table -> 8 blocks/CU)

// d_ws float layout:
//   [0]=lo0  [1]=inv  [2..3] pad
//   [WS_PAIR .. +2064)  float2 pairs {B[i], tab[i]}, i in [0,1032): 1023 real
//                       boundaries, [1023]=INF, 8 INF overrun pads
//   [WS_BKT  .. +2048)  4096 x u16 bucket->start-count table
#define WS_PAIR 4
#define WS_BKT  (WS_PAIR + 2*(NL+8))   // float idx 2068, byte 8272 (16B aligned)

// order-preserving float<->uint map (total order incl. negatives)
__device__ __forceinline__ unsigned oi(float f) {
    unsigned u = __float_as_uint(f);
    return (u & 0x80000000u) ? ~u : (u | 0x80000000u);
}
__device__ __forceinline__ float unoi(unsigned k) {
    return __uint_as_float((k & 0x80000000u) ? (k & 0x7fffffffu) : ~k);
}

// bucket index — MUST be the identical fp32 op sequence in build and main
// kernels (monotone: fp sub/mul-by-positive/trunc/clamp are all monotone).
__device__ __forceinline__ int bidx(float x, float lo0, float inv) {
    float t = (x - lo0) * inv;
    int j = (int)t;              // trunc toward zero; clamped below anyway
    j = j < 0 ? 0 : j;
    j = j > (NB - 1) ? (NB - 1) : j;
    return j;
}

// ---------------------------------------------------------------------------
// Build kernel (1 block, 1024 threads) — unchanged from R4.
// ---------------------------------------------------------------------------
__global__ __launch_bounds__(1024) void build_kernel(
    const float* __restrict__ h, const float* __restrict__ d,
    const float* __restrict__ T, const float* __restrict__ bp,
    float* __restrict__ ws)
{
    __shared__ float s_g[NL];
    __shared__ float s_B[NL];     // 1023 boundaries + [1023]=INF
    __shared__ int   s_jb[NL];    // bidx of each boundary + sentinel
    __shared__ float s_lo0, s_inv;

    const int tid = threadIdx.x;
    float g = h[tid * KP1];
    s_g[tid] = g;

    // 1. out-value table (exact replica of reference fp32 sequence)
    float outv;
    {
        float v = g, o = 0.0f, b = bp[0];
#pragma unroll
        for (int t = 1; t <= 8; ++t) {
            float z = ((v - T[t]) >= 0.0f) ? 1.0f : 0.0f;
            o = o + z * d[t];
            if (t != 8) v = h[tid * KP1 + (t + 1)];
        }
        outv = o - b;
    }
    __syncthreads();

    // 2. exact fp32 decision boundary per adjacent pair
    if (tid < NL - 1) {
        float l = s_g[tid], r = s_g[tid + 1];
        unsigned a = oi(l), b2 = oi(r);   // predicate false at l, true at r
        while (a < b2) {
            unsigned m = a + ((b2 - a) >> 1);
            float xm = unoi(m);
            float dl = fabsf(xm - l), dr = fabsf(xm - r);
            if (!(dl < dr)) b2 = m; else a = m + 1;
        }
        s_B[tid] = unoi(a);
    } else {
        s_B[tid] = INFINITY;
    }
    __syncthreads();

    if (tid == 0) {
        float lo0 = s_B[0];
        float inv = (float)NB / (s_B[NL - 2] - lo0);
        s_lo0 = lo0; s_inv = inv;
        ws[0] = lo0; ws[1] = inv;
    }
    __syncthreads();

    float lo0 = s_lo0, inv = s_inv;
    s_jb[tid] = (tid < NL - 1) ? bidx(s_B[tid], lo0, inv) : 0x7fffffff;

    // 3. interleaved {boundary, value} pairs + overrun pads
    ws[WS_PAIR + 2 * tid]     = s_B[tid];
    ws[WS_PAIR + 2 * tid + 1] = outv;
    if (tid < 8) {
        ws[WS_PAIR + 2 * (NL + tid)]     = INFINITY;
        ws[WS_PAIR + 2 * (NL + tid) + 1] = 0.0f;
    }
    __syncthreads();

    // 4. bucket start counts: lower_bound over sorted s_jb
    unsigned short* bucket = (unsigned short*)(ws + WS_BKT);
    for (int j = tid; j < NB; j += 1024) {
        int lo = 0;
#pragma unroll
        for (int s = 512; s >= 1; s >>= 1)
            if (s_jb[lo + s - 1] < j) lo += s;
        bucket[j] = (unsigned short)lo;
    }
}

// ---------------------------------------------------------------------------
// Main kernel. Round-6: FORCE memory-level parallelism.
// R0-R5 all pinned at 82-90 us; every compiled form had only 1-2 x-loads in
// flight per wave (R3's pipeline was compiler-sunk, VGPR=16). Little's law:
// ~2 KB/wave outstanding at ~375 ns latency = ~2.3 TB/s -- exactly the
// measured 2.35-2.46 TB/s every round. R2's scratch traffic streamed at
// ~5.5 TB/s marginal, proving HBM headroom.
// Fix: n4 == 8 * gridDim*blockDim exactly, so NO loop: load all 8 float4s
// up front, pin them with an empty asm register barrier (compiler cannot
// sink the loads), one vmcnt wait, then 8 lookup passes + stores.
// 8 KB/wave in flight x 32 waves/CU = 256 KB/CU outstanding -> BW-bound.
// LDS = 8.3 KB pairs + 8 KB buckets ~= 16.5 KB -> 8 blocks/CU (32 waves).
// ---------------------------------------------------------------------------
typedef float vf4 __attribute__((ext_vector_type(4)));

__device__ __forceinline__ float4 proc4(float4 v,
                                        const float2* __restrict__ pp,
                                        const unsigned short* __restrict__ sbk,
                                        float lo0, float inv)
{
    // phase 1: 4 bucket reads issue together
    int n0 = sbk[bidx(v.x, lo0, inv)];
    int n1 = sbk[bidx(v.y, lo0, inv)];
    int n2 = sbk[bidx(v.z, lo0, inv)];
    int n3 = sbk[bidx(v.w, lo0, inv)];
    // phase 2: 8 independent b64 candidate reads issue together
    float2 a0 = pp[n0], b0 = pp[n0 + 1];
    float2 a1 = pp[n1], b1 = pp[n1 + 1];
    float2 a2 = pp[n2], b2 = pp[n2 + 1];
    float2 a3 = pp[n3], b3 = pp[n3 + 1];
    // phase 3: branch-free select (B sorted: B[n] <= B[n+1])
    float r0 = (a0.x > v.x) ? a0.y : b0.y;
    float r1 = (a1.x > v.y) ? a1.y : b1.y;
    float r2 = (a2.x > v.z) ? a2.y : b2.y;
    float r3 = (a3.x > v.w) ? a3.y : b3.y;
    // phase 4: rare fallback (~0.9%/lane) when neither candidate terminates
    bool f0 = (b0.x <= v.x), f1 = (b1.x <= v.y);
    bool f2 = (b2.x <= v.z), f3 = (b3.x <= v.w);
    if (__builtin_expect(f0 | f1 | f2 | f3, 0)) {
        if (f0) { int m = n0 + 2; float2 p = pp[m];
                  while (p.x <= v.x) { ++m; p = pp[m]; } r0 = p.y; }
        if (f1) { int m = n1 + 2; float2 p = pp[m];
                  while (p.x <= v.y) { ++m; p = pp[m]; } r1 = p.y; }
        if (f2) { int m = n2 + 2; float2 p = pp[m];
                  while (p.x <= v.z) { ++m; p = pp[m]; } r2 = p.y; }
        if (f3) { int m = n3 + 2; float2 p = pp[m];
                  while (p.x <= v.w) { ++m; p = pp[m]; } r3 = p.y; }
    }
    return make_float4(r0, r1, r2, r3);
}

__global__ __launch_bounds__(256) void ps_act_kernel(
    const float* __restrict__ x,
    const float* __restrict__ ws,
    float* __restrict__ out,
    int n4)
{
    __shared__ __align__(16) float          spair[2 * (NL + 8)];
    __shared__ __align__(16) unsigned short sbk[NB];

    const int tid = threadIdx.x;
    // vectorized staging: 516 float4s of pairs, 512 uint4s of buckets
    {
        const float4* wp4 = (const float4*)(ws + WS_PAIR);
        float4* sp4 = (float4*)spair;
        for (int i = tid; i < 2 * (NL + 8) / 4; i += 256) sp4[i] = wp4[i];
        const uint4* wb4 = (const uint4*)(ws + WS_BKT);
        uint4* sb4 = (uint4*)sbk;
        for (int i = tid; i < NB * 2 / 16; i += 256) sb4[i] = wb4[i];
    }
    const float lo0 = ws[0];
    const float inv = ws[1];
    __syncthreads();

    const float4* __restrict__ x4 = (const float4*)x;
    float4* __restrict__ o4 = (float4*)out;
    const float2* pp = (const float2*)spair;
    const int stride = gridDim.x * blockDim.x;   // 1048576
    const int base = blockIdx.x * blockDim.x + tid;

    // ---- issue ALL 8 loads up front (8 KB/wave outstanding) ----
    vf4 c0 = {0,0,0,0}, c1 = {0,0,0,0}, c2 = {0,0,0,0}, c3 = {0,0,0,0};
    vf4 c4 = {0,0,0,0}, c5 = {0,0,0,0}, c6 = {0,0,0,0}, c7 = {0,0,0,0};
    const int i0 = base;
    const int i1 = base + 1 * stride;
    const int i2 = base + 2 * stride;
    const int i3 = base + 3 * stride;
    const int i4_ = base + 4 * stride;
    const int i5 = base + 5 * stride;
    const int i6 = base + 6 * stride;
    const int i7 = base + 7 * stride;
    if (i0 < n4)  c0 = *(const vf4*)&x4[i0];
    if (i1 < n4)  c1 = *(const vf4*)&x4[i1];
    if (i2 < n4)  c2 = *(const vf4*)&x4[i2];
    if (i3 < n4)  c3 = *(const vf4*)&x4[i3];
    if (i4_ < n4) c4 = *(const vf4*)&x4[i4_];
    if (i5 < n4)  c5 = *(const vf4*)&x4[i5];
    if (i6 < n4)  c6 = *(const vf4*)&x4[i6];
    if (i7 < n4)  c7 = *(const vf4*)&x4[i7];
    // register barrier: pins all 8 loads as materialized here — compiler
    // cannot sink them to their uses (rule #17 anti-DCE/anti-sink trick)
    asm volatile("" : "+v"(c0), "+v"(c1), "+v"(c2), "+v"(c3),
                      "+v"(c4), "+v"(c5), "+v"(c6), "+v"(c7));

#define PROC_STORE(ci, ii)                                                  \
    if ((ii) < n4) {                                                        \
        float4 vv = make_float4((ci).x, (ci).y, (ci).z, (ci).w);            \
        float4 rr = proc4(vv, pp, sbk, lo0, inv);                           \
        vf4 oo = {rr.x, rr.y, rr.z, rr.w};                                  \
        __builtin_nontemporal_store(oo, (vf4*)&o4[ii]);                     \
    }

    PROC_STORE(c0, i0)
    PROC_STORE(c1, i1)
    PROC_STORE(c2, i2)
    PROC_STORE(c3, i3)
    PROC_STORE(c4, i4_)
    PROC_STORE(c5, i5)
    PROC_STORE(c6, i6)
    PROC_STORE(c7, i7)
#undef PROC_STORE
}

extern "C" void kernel_launch(void* const* d_in, const int* in_sizes, int n_in,
                              void* d_out, int out_size, void* d_ws, size_t ws_size,
                              hipStream_t stream) {
    const float* x = (const float*)d_in[0];
    const float* h = (const float*)d_in[1];
    const float* d = (const float*)d_in[2];
    const float* T = (const float*)d_in[3];
    const float* b = (const float*)d_in[4];
    float* out = (float*)d_out;
    float* ws  = (float*)d_ws;

    int n  = in_sizes[0];
    int n4 = n / 4;

    build_kernel<<<1, 1024, 0, stream>>>(h, d, T, b, ws);
    // 4096 blocks x 256 threads x 8 float4 = n4 exactly: flat, loop-free.
    ps_act_kernel<<<4096, 256, 0, stream>>>(x, ws, out, n4);
}

// Round 7
// 258.290 us; speedup vs baseline: 1.0052x; 1.0052x over previous
//
#include <hip/hip_runtime.h>
#include <math.h>

#define NL  1024     // N_LEVELS
#define KP1 9        // K+1
#define NB  4096     // direct-mapped buckets (8 KB u16 table -> 8 blocks/CU)

// d_ws float layout:
//   [0]=lo0  [1]=inv  [2..3] pad
//   [WS_PAIR .. +2064)  float2 pairs {B[i], tab[i]}, i in [0,1032): 1023 real
//                       boundaries, [1023]=INF, 8 INF overrun pads
//   [WS_BKT  .. +2048)  4096 x u16 bucket->start-count table
#define WS_PAIR 4
#define WS_BKT  (WS_PAIR + 2*(NL+8))   // float idx 2068, byte 8272 (16B aligned)

// order-preserving float<->uint map (total order incl. negatives)
__device__ __forceinline__ unsigned oi(float f) {
    unsigned u = __float_as_uint(f);
    return (u & 0x80000000u) ? ~u : (u | 0x80000000u);
}
__device__ __forceinline__ float unoi(unsigned k) {
    return __uint_as_float((k & 0x80000000u) ? (k & 0x7fffffffu) : ~k);
}

// bucket index — MUST be the identical fp32 op sequence in build and main
// kernels (monotone: fp sub/mul-by-positive/trunc/clamp are all monotone).
__device__ __forceinline__ int bidx(float x, float lo0, float inv) {
    float t = (x - lo0) * inv;
    int j = (int)t;              // trunc toward zero; clamped below anyway
    j = j < 0 ? 0 : j;
    j = j > (NB - 1) ? (NB - 1) : j;
    return j;
}

// ---------------------------------------------------------------------------
// Build kernel (1 block, 1024 threads) — unchanged from R4.
// ---------------------------------------------------------------------------
__global__ __launch_bounds__(1024) void build_kernel(
    const float* __restrict__ h, const float* __restrict__ d,
    const float* __restrict__ T, const float* __restrict__ bp,
    float* __restrict__ ws)
{
    __shared__ float s_g[NL];
    __shared__ float s_B[NL];     // 1023 boundaries + [1023]=INF
    __shared__ int   s_jb[NL];    // bidx of each boundary + sentinel
    __shared__ float s_lo0, s_inv;

    const int tid = threadIdx.x;
    float g = h[tid * KP1];
    s_g[tid] = g;

    // 1. out-value table (exact replica of reference fp32 sequence)
    float outv;
    {
        float v = g, o = 0.0f, b = bp[0];
#pragma unroll
        for (int t = 1; t <= 8; ++t) {
            float z = ((v - T[t]) >= 0.0f) ? 1.0f : 0.0f;
            o = o + z * d[t];
            if (t != 8) v = h[tid * KP1 + (t + 1)];
        }
        outv = o - b;
    }
    __syncthreads();

    // 2. exact fp32 decision boundary per adjacent pair
    if (tid < NL - 1) {
        float l = s_g[tid], r = s_g[tid + 1];
        unsigned a = oi(l), b2 = oi(r);   // predicate false at l, true at r
        while (a < b2) {
            unsigned m = a + ((b2 - a) >> 1);
            float xm = unoi(m);
            float dl = fabsf(xm - l), dr = fabsf(xm - r);
            if (!(dl < dr)) b2 = m; else a = m + 1;
        }
        s_B[tid] = unoi(a);
    } else {
        s_B[tid] = INFINITY;
    }
    __syncthreads();

    if (tid == 0) {
        float lo0 = s_B[0];
        float inv = (float)NB / (s_B[NL - 2] - lo0);
        s_lo0 = lo0; s_inv = inv;
        ws[0] = lo0; ws[1] = inv;
    }
    __syncthreads();

    float lo0 = s_lo0, inv = s_inv;
    s_jb[tid] = (tid < NL - 1) ? bidx(s_B[tid], lo0, inv) : 0x7fffffff;

    // 3. interleaved {boundary, value} pairs + overrun pads
    ws[WS_PAIR + 2 * tid]     = s_B[tid];
    ws[WS_PAIR + 2 * tid + 1] = outv;
    if (tid < 8) {
        ws[WS_PAIR + 2 * (NL + tid)]     = INFINITY;
        ws[WS_PAIR + 2 * (NL + tid) + 1] = 0.0f;
    }
    __syncthreads();

    // 4. bucket start counts: lower_bound over sorted s_jb
    unsigned short* bucket = (unsigned short*)(ws + WS_BKT);
    for (int j = tid; j < NB; j += 1024) {
        int lo = 0;
#pragma unroll
        for (int s = 512; s >= 1; s >>= 1)
            if (s_jb[lo + s - 1] < j) lo += s;
        bucket[j] = (unsigned short)lo;
    }
}

// ---------------------------------------------------------------------------
// Main kernel. Round-7: depth-8 load pipeline with COUNTED waits.
// R6 post-mortem: the joint "+v" asm barrier forced s_waitcnt vmcnt(0)
// (full drain) before any processing -> convoy, bw DROPPED. The T4 lesson:
// counted vmcnt, never drain-0. Plain-HIP recipe:
//   (a) exact-fit grid -> 8 UNCONDITIONAL straight-line loads (no control
//       flow for the compiler to sink them under, unlike R3/R6 guards);
//   (b) asm volatile("" ::: "memory") pins load ISSUE before it without
//       touching register values -> no forced drain (reads cannot be
//       reordered past a potential write, but no value is consumed);
//   (c) proc+store in load order -> compiler emits its documented minimal
//       counted waits (vmcnt(7), vmcnt(6), ...): c1..c7 stay in flight
//       while the wave does c0's ~600cy of LDS work.
// LDS = 8.3 KB pairs + 8 KB buckets ~= 16.5 KB -> 8 blocks/CU (32 waves).
// ---------------------------------------------------------------------------
typedef float vf4 __attribute__((ext_vector_type(4)));

__device__ __forceinline__ float4 proc4(float4 v,
                                        const float2* __restrict__ pp,
                                        const unsigned short* __restrict__ sbk,
                                        float lo0, float inv)
{
    // phase 1: 4 bucket reads issue together
    int n0 = sbk[bidx(v.x, lo0, inv)];
    int n1 = sbk[bidx(v.y, lo0, inv)];
    int n2 = sbk[bidx(v.z, lo0, inv)];
    int n3 = sbk[bidx(v.w, lo0, inv)];
    // phase 2: 8 independent b64 candidate reads issue together
    float2 a0 = pp[n0], b0 = pp[n0 + 1];
    float2 a1 = pp[n1], b1 = pp[n1 + 1];
    float2 a2 = pp[n2], b2 = pp[n2 + 1];
    float2 a3 = pp[n3], b3 = pp[n3 + 1];
    // phase 3: branch-free select (B sorted: B[n] <= B[n+1])
    float r0 = (a0.x > v.x) ? a0.y : b0.y;
    float r1 = (a1.x > v.y) ? a1.y : b1.y;
    float r2 = (a2.x > v.z) ? a2.y : b2.y;
    float r3 = (a3.x > v.w) ? a3.y : b3.y;
    // phase 4: rare fallback (~0.9%/lane) when neither candidate terminates
    bool f0 = (b0.x <= v.x), f1 = (b1.x <= v.y);
    bool f2 = (b2.x <= v.z), f3 = (b3.x <= v.w);
    if (__builtin_expect(f0 | f1 | f2 | f3, 0)) {
        if (f0) { int m = n0 + 2; float2 p = pp[m];
                  while (p.x <= v.x) { ++m; p = pp[m]; } r0 = p.y; }
        if (f1) { int m = n1 + 2; float2 p = pp[m];
                  while (p.x <= v.y) { ++m; p = pp[m]; } r1 = p.y; }
        if (f2) { int m = n2 + 2; float2 p = pp[m];
                  while (p.x <= v.z) { ++m; p = pp[m]; } r2 = p.y; }
        if (f3) { int m = n3 + 2; float2 p = pp[m];
                  while (p.x <= v.w) { ++m; p = pp[m]; } r3 = p.y; }
    }
    return make_float4(r0, r1, r2, r3);
}

__global__ __launch_bounds__(256) void ps_act_kernel(
    const float* __restrict__ x,
    const float* __restrict__ ws,
    float* __restrict__ out,
    int n4)
{
    __shared__ __align__(16) float          spair[2 * (NL + 8)];
    __shared__ __align__(16) unsigned short sbk[NB];

    const int tid = threadIdx.x;
    // vectorized staging: 516 float4s of pairs, 512 uint4s of buckets
    {
        const float4* wp4 = (const float4*)(ws + WS_PAIR);
        float4* sp4 = (float4*)spair;
        for (int i = tid; i < 2 * (NL + 8) / 4; i += 256) sp4[i] = wp4[i];
        const uint4* wb4 = (const uint4*)(ws + WS_BKT);
        uint4* sb4 = (uint4*)sbk;
        for (int i = tid; i < NB * 2 / 16; i += 256) sb4[i] = wb4[i];
    }
    const float lo0 = ws[0];
    const float inv = ws[1];
    __syncthreads();

    const float4* __restrict__ x4 = (const float4*)x;
    float4* __restrict__ o4 = (float4*)out;
    const float2* pp = (const float2*)spair;
    const int stride = gridDim.x * blockDim.x;
    const int base = blockIdx.x * blockDim.x + tid;

    if (n4 == 8 * stride) {
        // ---- fast path: straight-line, unconditional ----
        const float4* xp = x4 + base;
        float4* op = o4 + base;

        // 8 independent loads issue back-to-back (8 KB/wave outstanding)
        float4 c0 = xp[0 * stride];
        float4 c1 = xp[1 * stride];
        float4 c2 = xp[2 * stride];
        float4 c3 = xp[3 * stride];
        float4 c4 = xp[4 * stride];
        float4 c5 = xp[5 * stride];
        float4 c6 = xp[6 * stride];
        float4 c7 = xp[7 * stride];
        // compiler memory barrier: loads may not sink below this point,
        // but NO register value is consumed -> no forced vmcnt(0) drain.
        asm volatile("" ::: "memory");

#define PROC_ST(ci, k)                                                      \
        {                                                                   \
            float4 rr = proc4(ci, pp, sbk, lo0, inv);                       \
            vf4 oo = {rr.x, rr.y, rr.z, rr.w};                              \
            __builtin_nontemporal_store(oo, (vf4*)&op[(k) * stride]);       \
        }
        // consume in load order -> counted waits vmcnt(7), vmcnt(6), ...
        PROC_ST(c0, 0)
        PROC_ST(c1, 1)
        PROC_ST(c2, 2)
        PROC_ST(c3, 3)
        PROC_ST(c4, 4)
        PROC_ST(c5, 5)
        PROC_ST(c6, 6)
        PROC_ST(c7, 7)
#undef PROC_ST
    } else {
        // ---- generic fallback: R4 loop ----
        for (int i4 = base; i4 < n4; i4 += 2 * stride) {
            const int j4 = i4 + stride;
            float4 c0 = x4[i4];
            float4 c1 = make_float4(0.f, 0.f, 0.f, 0.f);
            if (j4 < n4) c1 = x4[j4];

            float4 r0 = proc4(c0, pp, sbk, lo0, inv);
            vf4 o0 = {r0.x, r0.y, r0.z, r0.w};
            __builtin_nontemporal_store(o0, (vf4*)&o4[i4]);

            if (j4 < n4) {
                float4 r1 = proc4(c1, pp, sbk, lo0, inv);
                vf4 o1 = {r1.x, r1.y, r1.z, r1.w};
                __builtin_nontemporal_store(o1, (vf4*)&o4[j4]);
            }
        }
    }
}

extern "C" void kernel_launch(void* const* d_in, const int* in_sizes, int n_in,
                              void* d_out, int out_size, void* d_ws, size_t ws_size,
                              hipStream_t stream) {
    const float* x = (const float*)d_in[0];
    const float* h = (const float*)d_in[1];
    const float* d = (const float*)d_in[2];
    const float* T = (const float*)d_in[3];
    const float* b = (const float*)d_in[4];
    float* out = (float*)d_out;
    float* ws  = (float*)d_ws;

    int n  = in_sizes[0];
    int n4 = n / 4;

    build_kernel<<<1, 1024, 0, stream>>>(h, d, T, b, ws);
    // 4096 blocks x 256 threads x 8 float4 = n4 exactly: straight-line
    // depth-8 counted-vmcnt pipeline per wave.
    ps_act_kernel<<<4096, 256, 0, stream>>>(x, ws, out, n4);
}

// Round 8
// 254.292 us; speedup vs baseline: 1.0210x; 1.0157x over previous
//
#include <hip/hip_runtime.h>
#include <math.h>

#define NL  1024     // N_LEVELS
#define KP1 9        // K+1
#define NB  2048     // direct-mapped buckets (4 KB u16 table)

// d_ws float layout:
//   [0]=lo0  [1]=inv  [2..3] pad
//   [WS_PAIR .. +2064)  float2 pairs {B[i], tab[i]}, i in [0,1032): 1023 real
//                       boundaries, [1023]=INF, 8 INF overrun pads
//   [WS_BKT  .. +1024)  2048 x u16 bucket->start-count table
#define WS_PAIR 4
#define WS_BKT  (WS_PAIR + 2*(NL+8))   // float idx 2068, byte 8272 (16B aligned)

// order-preserving float<->uint map (total order incl. negatives)
__device__ __forceinline__ unsigned oi(float f) {
    unsigned u = __float_as_uint(f);
    return (u & 0x80000000u) ? ~u : (u | 0x80000000u);
}
__device__ __forceinline__ float unoi(unsigned k) {
    return __uint_as_float((k & 0x80000000u) ? (k & 0x7fffffffu) : ~k);
}

// bucket index — MUST be the identical fp32 op sequence in build and main
// kernels (monotone: fp sub/mul-by-positive/trunc/clamp are all monotone).
__device__ __forceinline__ int bidx(float x, float lo0, float inv) {
    float t = (x - lo0) * inv;
    int j = (int)t;              // trunc toward zero; clamped below anyway
    j = j < 0 ? 0 : j;
    j = j > (NB - 1) ? (NB - 1) : j;
    return j;
}

// ---------------------------------------------------------------------------
// Build kernel (1 block, 1024 threads) — same as R4, NB=2048.
// ---------------------------------------------------------------------------
__global__ __launch_bounds__(1024) void build_kernel(
    const float* __restrict__ h, const float* __restrict__ d,
    const float* __restrict__ T, const float* __restrict__ bp,
    float* __restrict__ ws)
{
    __shared__ float s_g[NL];
    __shared__ float s_B[NL];     // 1023 boundaries + [1023]=INF
    __shared__ int   s_jb[NL];    // bidx of each boundary + sentinel
    __shared__ float s_lo0, s_inv;

    const int tid = threadIdx.x;
    float g = h[tid * KP1];
    s_g[tid] = g;

    // 1. out-value table (exact replica of reference fp32 sequence)
    float outv;
    {
        float v = g, o = 0.0f, b = bp[0];
#pragma unroll
        for (int t = 1; t <= 8; ++t) {
            float z = ((v - T[t]) >= 0.0f) ? 1.0f : 0.0f;
            o = o + z * d[t];
            if (t != 8) v = h[tid * KP1 + (t + 1)];
        }
        outv = o - b;
    }
    __syncthreads();

    // 2. exact fp32 decision boundary per adjacent pair
    if (tid < NL - 1) {
        float l = s_g[tid], r = s_g[tid + 1];
        unsigned a = oi(l), b2 = oi(r);   // predicate false at l, true at r
        while (a < b2) {
            unsigned m = a + ((b2 - a) >> 1);
            float xm = unoi(m);
            float dl = fabsf(xm - l), dr = fabsf(xm - r);
            if (!(dl < dr)) b2 = m; else a = m + 1;
        }
        s_B[tid] = unoi(a);
    } else {
        s_B[tid] = INFINITY;
    }
    __syncthreads();

    if (tid == 0) {
        float lo0 = s_B[0];
        float inv = (float)NB / (s_B[NL - 2] - lo0);
        s_lo0 = lo0; s_inv = inv;
        ws[0] = lo0; ws[1] = inv;
    }
    __syncthreads();

    float lo0 = s_lo0, inv = s_inv;
    s_jb[tid] = (tid < NL - 1) ? bidx(s_B[tid], lo0, inv) : 0x7fffffff;

    // 3. interleaved {boundary, value} pairs + overrun pads
    ws[WS_PAIR + 2 * tid]     = s_B[tid];
    ws[WS_PAIR + 2 * tid + 1] = outv;
    if (tid < 8) {
        ws[WS_PAIR + 2 * (NL + tid)]     = INFINITY;
        ws[WS_PAIR + 2 * (NL + tid) + 1] = 0.0f;
    }
    __syncthreads();

    // 4. bucket start counts: lower_bound over sorted s_jb
    unsigned short* bucket = (unsigned short*)(ws + WS_BKT);
    for (int j = tid; j < NB; j += 1024) {
        int lo = 0;
#pragma unroll
        for (int s = 512; s >= 1; s >>= 1)
            if (s_jb[lo + s - 1] < j) lo += s;
        bucket[j] = (unsigned short)lo;
    }
}

// ---------------------------------------------------------------------------
// Main kernel. Round-8: global_load_lds ring pipeline (cp.async pattern).
// Every compiler-scheduled load pipeline (R3/R6/R7) was sunk or drain-
// serialized. The DMA intrinsic is side-effecting: hipcc cannot sink/merge
// it, and asm memory clobbers pin the issue order, so the counted vmcnt
// numbers below are exact by construction (T4: never drain to 0 mid-loop).
// 4-slot ring: loads run 3-4 tiles (~1800 cy) ahead of consumption.
// Each thread reads back ONLY its own 16B slot -> no block barrier in the
// loop; the staging __syncthreads drains vmcnt so counts start at 0.
// LDS = 8.3 KB pairs + 4 KB buckets + 16 KB ring = 28.7 KB -> 5 blocks/CU.
// ---------------------------------------------------------------------------
typedef float vf4 __attribute__((ext_vector_type(4)));

#define WAIT_VMCNT(n) asm volatile("s_waitcnt vmcnt(" #n ")" ::: "memory")

__device__ __forceinline__ float4 proc4(float4 v,
                                        const float2* __restrict__ pp,
                                        const unsigned short* __restrict__ sbk,
                                        float lo0, float inv)
{
    // phase 1: 4 bucket reads issue together
    int n0 = sbk[bidx(v.x, lo0, inv)];
    int n1 = sbk[bidx(v.y, lo0, inv)];
    int n2 = sbk[bidx(v.z, lo0, inv)];
    int n3 = sbk[bidx(v.w, lo0, inv)];
    // phase 2: 8 independent b64 candidate reads issue together
    float2 a0 = pp[n0], b0 = pp[n0 + 1];
    float2 a1 = pp[n1], b1 = pp[n1 + 1];
    float2 a2 = pp[n2], b2 = pp[n2 + 1];
    float2 a3 = pp[n3], b3 = pp[n3 + 1];
    // phase 3: branch-free select (B sorted: B[n] <= B[n+1])
    float r0 = (a0.x > v.x) ? a0.y : b0.y;
    float r1 = (a1.x > v.y) ? a1.y : b1.y;
    float r2 = (a2.x > v.z) ? a2.y : b2.y;
    float r3 = (a3.x > v.w) ? a3.y : b3.y;
    // phase 4: rare fallback (~3%/lane at NB=2048), exec-masked
    bool f0 = (b0.x <= v.x), f1 = (b1.x <= v.y);
    bool f2 = (b2.x <= v.z), f3 = (b3.x <= v.w);
    if (__builtin_expect(f0 | f1 | f2 | f3, 0)) {
        if (f0) { int m = n0 + 2; float2 p = pp[m];
                  while (p.x <= v.x) { ++m; p = pp[m]; } r0 = p.y; }
        if (f1) { int m = n1 + 2; float2 p = pp[m];
                  while (p.x <= v.y) { ++m; p = pp[m]; } r1 = p.y; }
        if (f2) { int m = n2 + 2; float2 p = pp[m];
                  while (p.x <= v.z) { ++m; p = pp[m]; } r2 = p.y; }
        if (f3) { int m = n3 + 2; float2 p = pp[m];
                  while (p.x <= v.w) { ++m; p = pp[m]; } r3 = p.y; }
    }
    return make_float4(r0, r1, r2, r3);
}

__global__ __launch_bounds__(256) void ps_act_kernel(
    const float* __restrict__ x,
    const float* __restrict__ ws,
    float* __restrict__ out,
    int n4)
{
    __shared__ __align__(16) float          spair[2 * (NL + 8)];  // 8256 B
    __shared__ __align__(16) unsigned short sbk[NB];              // 4096 B
    __shared__ __align__(16) float          xbuf[4 * 1024];       // 16 KB ring

    const int tid = threadIdx.x;
    // vectorized staging: 516 float4s of pairs, 256 uint4s of buckets
    {
        const float4* wp4 = (const float4*)(ws + WS_PAIR);
        float4* sp4 = (float4*)spair;
        for (int i = tid; i < 2 * (NL + 8) / 4; i += 256) sp4[i] = wp4[i];
        const uint4* wb4 = (const uint4*)(ws + WS_BKT);
        uint4* sb4 = (uint4*)sbk;
        for (int i = tid; i < NB * 2 / 16; i += 256) sb4[i] = wb4[i];
    }
    const float lo0 = ws[0];
    const float inv = ws[1];
    __syncthreads();   // implies full vmcnt drain: DMA counting starts at 0

    const float4* __restrict__ x4 = (const float4*)x;
    float4* __restrict__ o4 = (float4*)out;
    const float2* pp = (const float2*)spair;
    const int stride = gridDim.x * blockDim.x;          // 1048576
    const int gbase  = blockIdx.x * blockDim.x + tid;
    // wave-uniform LDS base for the DMA (HW writes base + lane*16)
    const int wslot  = (tid >> 6) << 8;   // wave's 256-float region in a slot

    if (n4 == 8 * stride) {
        // ---- prologue: DMA tiles 0..3 into ring slots 0..3 ----
#pragma unroll
        for (int t = 0; t < 4; ++t)
            __builtin_amdgcn_global_load_lds(
                (const float*)(x4 + ((long)t * stride + gbase)),
                &xbuf[t * 1024 + wslot], 16, 0, 0);
        asm volatile("" ::: "memory");

#define STEP(t, WAITMACRO, PREFETCH)                                        \
        {                                                                   \
            WAITMACRO;                                                      \
            float4 c = *(const float4*)&xbuf[((t) & 3) * 1024 + (tid << 2)];\
            float4 r = proc4(c, pp, sbk, lo0, inv);                         \
            vf4 oo = {r.x, r.y, r.z, r.w};                                  \
            __builtin_nontemporal_store(                                    \
                oo, (vf4*)&o4[(long)(t) * stride + gbase]);                 \
            if (PREFETCH)                                                   \
                __builtin_amdgcn_global_load_lds(                           \
                    (const float*)(x4 + ((long)((t)+4) * stride + gbase)),  \
                    &xbuf[((t) & 3) * 1024 + wslot], 16, 0, 0);             \
            asm volatile("" ::: "memory");                                  \
        }
        // counted waits = #vmem ops issued after the needed DMA (exact):
        STEP(0, WAIT_VMCNT(3), 1)   // outstanding allowed: DMA1-3
        STEP(1, WAIT_VMCNT(4), 1)   // DMA2,DMA3,store0,DMA4
        STEP(2, WAIT_VMCNT(5), 1)   // DMA3,s0,DMA4,s1,DMA5
        STEP(3, WAIT_VMCNT(6), 1)   // s0,DMA4,s1,DMA5,s2,DMA6
        STEP(4, WAIT_VMCNT(6), 0)   // s1,DMA5,s2,DMA6,s3,DMA7
        STEP(5, WAIT_VMCNT(5), 0)   // s2,DMA6,s3,DMA7,s4
        STEP(6, WAIT_VMCNT(4), 0)   // s3,DMA7,s4,s5
        STEP(7, WAIT_VMCNT(3), 0)   // s4,s5,s6
#undef STEP
    } else {
        // ---- generic fallback: R4 loop (no ring) ----
        for (int i4 = gbase; i4 < n4; i4 += 2 * stride) {
            const int j4 = i4 + stride;
            float4 c0 = x4[i4];
            float4 c1 = make_float4(0.f, 0.f, 0.f, 0.f);
            if (j4 < n4) c1 = x4[j4];

            float4 r0 = proc4(c0, pp, sbk, lo0, inv);
            vf4 o0 = {r0.x, r0.y, r0.z, r0.w};
            __builtin_nontemporal_store(o0, (vf4*)&o4[i4]);

            if (j4 < n4) {
                float4 r1 = proc4(c1, pp, sbk, lo0, inv);
                vf4 o1 = {r1.x, r1.y, r1.z, r1.w};
                __builtin_nontemporal_store(o1, (vf4*)&o4[j4]);
            }
        }
    }
}

extern "C" void kernel_launch(void* const* d_in, const int* in_sizes, int n_in,
                              void* d_out, int out_size, void* d_ws, size_t ws_size,
                              hipStream_t stream) {
    const float* x = (const float*)d_in[0];
    const float* h = (const float*)d_in[1];
    const float* d = (const float*)d_in[2];
    const float* T = (const float*)d_in[3];
    const float* b = (const float*)d_in[4];
    float* out = (float*)d_out;
    float* ws  = (float*)d_ws;

    int n  = in_sizes[0];
    int n4 = n / 4;

    build_kernel<<<1, 1024, 0, stream>>>(h, d, T, b, ws);
    // 4096 blocks x 256 threads x 8 float4 = n4 exactly: 4-deep DMA ring,
    // counted vmcnt, no in-loop barriers.
    ps_act_kernel<<<4096, 256, 0, stream>>>(x, ws, out, n4);
}